// Round 1
// baseline (1212.090 us; speedup 1.0000x reference)
//
#include <hip/hip_runtime.h>

#define HIDN 4096
#define CQD  1536
#define CKVD 512
#define NH   32
#define DH   128
#define DR   64
#define BATCH 16
#define SEQL 2048
#define HDR  (NH*DR)    // 2048
#define HDH  (NH*DH)    // 4096
#define LP1  (SEQL+1)   // 2049

// C[b,n] += sum_{k in this block's K-chunk} A[b,k] * W[k,n]
// grid.x = N/256, grid.y = K/256, block = 256. C must be zero-initialized.
__global__ __launch_bounds__(256) void gemm16_atomic(
    const float* __restrict__ A, const float* __restrict__ W,
    float* __restrict__ C, int K, int N) {
    const int KC = 256;
    __shared__ float sA[BATCH * KC];
    int n = blockIdx.x * 256 + threadIdx.x;
    int k0 = blockIdx.y * KC;
    for (int i = threadIdx.x; i < BATCH * KC; i += 256) {
        int b = i >> 8;
        int k = i & 255;
        sA[i] = A[b * K + k0 + k];
    }
    __syncthreads();
    float acc[BATCH];
#pragma unroll
    for (int b = 0; b < BATCH; ++b) acc[b] = 0.f;
    const float* Wp = W + (size_t)k0 * N + n;
    for (int k = 0; k < KC; ++k) {
        float w = Wp[(size_t)k * N];
#pragma unroll
        for (int b = 0; b < BATCH; ++b)
            acc[b] += sA[b * KC + k] * w;
    }
#pragma unroll
    for (int b = 0; b < BATCH; ++b)
        atomicAdd(&C[b * N + n], acc[b]);
}

// qC_eff[b,k] = sum_c qC[b,c] * W_UK_C[k,c]   (W_UK_C is (512,4096) row-major)
// one wave per k; grid = 512/4 blocks of 256 (4 waves)
__global__ __launch_bounds__(256) void qceff_kernel(
    const float* __restrict__ qC, const float* __restrict__ W_UK_C,
    float* __restrict__ qC_eff) {
    int wave = threadIdx.x >> 6;
    int lane = threadIdx.x & 63;
    int k = blockIdx.x * 4 + wave;
    const float* wrow = W_UK_C + (size_t)k * HDH;
    float acc[BATCH];
#pragma unroll
    for (int b = 0; b < BATCH; ++b) acc[b] = 0.f;
    for (int c = lane; c < HDH; c += 64) {
        float w = wrow[c];
#pragma unroll
        for (int b = 0; b < BATCH; ++b)
            acc[b] += qC[b * HDH + c] * w;
    }
#pragma unroll
    for (int b = 0; b < BATCH; ++b) {
        float v = acc[b];
#pragma unroll
        for (int off = 32; off > 0; off >>= 1)
            v += __shfl_down(v, off, 64);
        if (lane == 0) qC_eff[b * CKVD + k] = v;
    }
}

// Fused: score[b,l] = (qC_eff[b].cKV_row + qR[b].kR_row)/sqrt(192)
// AND copy the cache rows (incl. new token at l==SEQL) into d_out.
__global__ __launch_bounds__(256) void score_copy_kernel(
    const float* __restrict__ cached_cKV, const float* __restrict__ cached_kR,
    const float* __restrict__ cKV_t, const float* __restrict__ kR_t,
    const float* __restrict__ qC_eff, const float* __restrict__ qR,
    float* __restrict__ out_cKV, float* __restrict__ out_kR,
    float* __restrict__ scores) {
    int l = blockIdx.x;
    int b = blockIdx.y;
    int tid = threadIdx.x;
    const float4* ckv_row;
    const float4* kr_row;
    if (l < SEQL) {
        ckv_row = (const float4*)(cached_cKV + ((size_t)b * SEQL + l) * CKVD);
        kr_row  = (const float4*)(cached_kR  + ((size_t)b * SEQL + l) * HDR);
    } else {
        ckv_row = (const float4*)(cKV_t + b * CKVD);
        kr_row  = (const float4*)(kR_t + b * HDR);
    }
    float4* oc  = (float4*)(out_cKV + ((size_t)b * LP1 + l) * CKVD);
    float4* okr = (float4*)(out_kR  + ((size_t)b * LP1 + l) * HDR);
    const float4* qc4 = (const float4*)(qC_eff + b * CKVD);
    const float4* qr4 = (const float4*)(qR + b * HDR);
    float acc = 0.f;
    if (tid < 128) {                       // 512 floats = 128 float4
        float4 v = ckv_row[tid];
        float4 q = qc4[tid];
        acc += v.x*q.x + v.y*q.y + v.z*q.z + v.w*q.w;
        oc[tid] = v;
    }
#pragma unroll
    for (int j = 0; j < 2; ++j) {          // 2048 floats = 512 float4
        int i = tid + j * 256;
        float4 v = kr_row[i];
        float4 q = qr4[i];
        acc += v.x*q.x + v.y*q.y + v.z*q.z + v.w*q.w;
        okr[i] = v;
    }
    __shared__ float red[256];
    red[tid] = acc;
    __syncthreads();
    for (int s = 128; s > 0; s >>= 1) {
        if (tid < s) red[tid] += red[tid + s];
        __syncthreads();
    }
    if (tid == 0) scores[b * LP1 + l] = red[0] * 0.07216878364870323f; // 1/sqrt(192)
}

__global__ __launch_bounds__(256) void softmax_kernel(
    const float* __restrict__ scores, float* __restrict__ probs) {
    int b = blockIdx.x;
    int tid = threadIdx.x;
    __shared__ float red[256];
    float m = -1e30f;
    for (int i = tid; i < LP1; i += 256) m = fmaxf(m, scores[b * LP1 + i]);
    red[tid] = m; __syncthreads();
    for (int s = 128; s > 0; s >>= 1) {
        if (tid < s) red[tid] = fmaxf(red[tid], red[tid + s]);
        __syncthreads();
    }
    m = red[0]; __syncthreads();
    float sum = 0.f;
    for (int i = tid; i < LP1; i += 256) sum += __expf(scores[b * LP1 + i] - m);
    red[tid] = sum; __syncthreads();
    for (int s = 128; s > 0; s >>= 1) {
        if (tid < s) red[tid] += red[tid + s];
        __syncthreads();
    }
    float inv = 1.0f / red[0];
    for (int i = tid; i < LP1; i += 256)
        probs[b * LP1 + i] = __expf(scores[b * LP1 + i] - m) * inv;
}

// ctx[b,k] = sum_l probs[b,l] * newcache_cKV[b,l,k]  over all 2049 rows
__global__ __launch_bounds__(256) void ctx_kernel(
    const float* __restrict__ out_cKV, const float* __restrict__ probs,
    float* __restrict__ ctx) {
    int b = blockIdx.y;
    int l0 = blockIdx.x * 128;
    int tid = threadIdx.x;
    int lend = l0 + 128; if (lend > LP1) lend = LP1;
    float acc0 = 0.f, acc1 = 0.f;
    for (int l = l0; l < lend; ++l) {
        float p = probs[b * LP1 + l];
        const float* row = out_cKV + ((size_t)b * LP1 + l) * CKVD;
        acc0 += p * row[tid];
        acc1 += p * row[tid + 256];
    }
    atomicAdd(&ctx[b * CKVD + tid], acc0);
    atomicAdd(&ctx[b * CKVD + tid + 256], acc1);
}

extern "C" void kernel_launch(void* const* d_in, const int* in_sizes, int n_in,
                              void* d_out, int out_size, void* d_ws, size_t ws_size,
                              hipStream_t stream) {
    const float* hidden     = (const float*)d_in[0];
    const float* cached_cKV = (const float*)d_in[1];
    const float* cached_kR  = (const float*)d_in[2];
    const float* W_DQ   = (const float*)d_in[3];
    const float* W_DKV  = (const float*)d_in[4];
    const float* W_UQ_C = (const float*)d_in[5];
    const float* W_UQ_R = (const float*)d_in[6];
    const float* W_KR   = (const float*)d_in[7];
    const float* W_UK_C = (const float*)d_in[8];
    const float* W_UV_C = (const float*)d_in[9];
    const float* W_O    = (const float*)d_in[10];

    float* out     = (float*)d_out;                       // 16*4096
    float* out_cKV = out + BATCH * HDH;                   // 16*2049*512
    float* out_kR  = out_cKV + (size_t)BATCH * LP1 * CKVD;// 16*2049*2048

    float* ws      = (float*)d_ws;
    float* cQ      = ws;                       // 16*1536
    float* cKV_t   = cQ + BATCH * CQD;         // 16*512
    float* kR_t    = cKV_t + BATCH * CKVD;     // 16*2048
    float* qC      = kR_t + BATCH * HDR;       // 16*4096
    float* qR      = qC + BATCH * HDH;         // 16*2048
    float* qC_eff  = qR + BATCH * HDR;         // 16*512
    float* ctx     = qC_eff + BATCH * CKVD;    // 16*512
    float* tbuf    = ctx + BATCH * CKVD;       // 16*4096
    float* scores  = tbuf + BATCH * HDH;       // 16*2049
    float* probs   = scores + BATCH * LP1;     // 16*2049
    size_t n_ws_floats = (size_t)(probs + BATCH * LP1 - ws);

    hipMemsetAsync(d_ws, 0, n_ws_floats * sizeof(float), stream);
    hipMemsetAsync(d_out, 0, (size_t)BATCH * HDH * sizeof(float), stream);

    dim3 blk(256);
    gemm16_atomic<<<dim3(CQD / 256, HIDN / 256), blk, 0, stream>>>(hidden, W_DQ, cQ, HIDN, CQD);
    gemm16_atomic<<<dim3(CKVD / 256, HIDN / 256), blk, 0, stream>>>(hidden, W_DKV, cKV_t, HIDN, CKVD);
    gemm16_atomic<<<dim3(HDR / 256, HIDN / 256), blk, 0, stream>>>(hidden, W_KR, kR_t, HIDN, HDR);
    gemm16_atomic<<<dim3(HDH / 256, CQD / 256), blk, 0, stream>>>(cQ, W_UQ_C, qC, CQD, HDH);
    gemm16_atomic<<<dim3(HDR / 256, CQD / 256), blk, 0, stream>>>(cQ, W_UQ_R, qR, CQD, HDR);
    qceff_kernel<<<dim3(CKVD / 4), blk, 0, stream>>>(qC, W_UK_C, qC_eff);
    score_copy_kernel<<<dim3(LP1, BATCH), blk, 0, stream>>>(
        cached_cKV, cached_kR, cKV_t, kR_t, qC_eff, qR, out_cKV, out_kR, scores);
    softmax_kernel<<<dim3(BATCH), blk, 0, stream>>>(scores, probs);
    ctx_kernel<<<dim3((LP1 + 127) / 128, BATCH), blk, 0, stream>>>(out_cKV, probs, ctx);
    gemm16_atomic<<<dim3(HDH / 256, CKVD / 256), blk, 0, stream>>>(ctx, W_UV_C, tbuf, CKVD, HDH);
    gemm16_atomic<<<dim3(HIDN / 256, HDH / 256), blk, 0, stream>>>(tbuf, W_O, out, HDH, HIDN);
}

// Round 2
// 788.739 us; speedup vs baseline: 1.5367x; 1.5367x over previous
//
#include <hip/hip_runtime.h>

#define HIDN 4096
#define CQD  1536
#define CKVD 512
#define NH   32
#define DH   128
#define DR   64
#define BATCH 16
#define SEQL 2048
#define HDR  (NH*DR)    // 2048
#define HDH  (NH*DH)    // 4096
#define LP1  (SEQL+1)   // 2049

// ---------------------------------------------------------------------------
// Core: C[b, n..n+1] += sum_{k in chunk} A[b,k] * W[k, n..n+1]
// sA is k-major, b-contiguous: sA[k*16+b] -> 4x ds_read_b128 broadcast per k.
// ---------------------------------------------------------------------------
__device__ __forceinline__ void gemm16_core(
    const float* __restrict__ A, int K, int k0, int KC,
    const float* __restrict__ W, int ldW, int wcol,
    float* __restrict__ C, int ldC, int ccol,
    float* sA, int tid) {
    for (int i = tid; i < KC * 16; i += 256) {
        int k = i >> 4, b = i & 15;
        sA[i] = A[b * K + k0 + k];
    }
    __syncthreads();
    float2 acc[16];
#pragma unroll
    for (int b = 0; b < 16; ++b) acc[b] = make_float2(0.f, 0.f);
    const float* Wp = W + (size_t)k0 * ldW + wcol;
    const float4* sA4 = (const float4*)sA;
#pragma unroll 4
    for (int k = 0; k < KC; ++k) {
        float2 w = *(const float2*)(Wp + (size_t)k * ldW);
        float av[16];
        *(float4*)&av[0]  = sA4[k * 4 + 0];
        *(float4*)&av[4]  = sA4[k * 4 + 1];
        *(float4*)&av[8]  = sA4[k * 4 + 2];
        *(float4*)&av[12] = sA4[k * 4 + 3];
#pragma unroll
        for (int b = 0; b < 16; ++b) {
            acc[b].x += av[b] * w.x;
            acc[b].y += av[b] * w.y;
        }
    }
#pragma unroll
    for (int b = 0; b < 16; ++b) {
        atomicAdd(&C[b * ldC + ccol],     acc[b].x);
        atomicAdd(&C[b * ldC + ccol + 1], acc[b].y);
    }
}

// Fused: cQ = h@W_DQ, cKV_t = h@W_DKV, kR_t = h@W_KR.  grid (8, 32), KC=128
__global__ __launch_bounds__(256) void proj_hidden(
    const float* __restrict__ hidden,
    const float* __restrict__ W_DQ, const float* __restrict__ W_DKV,
    const float* __restrict__ W_KR,
    float* __restrict__ cQ, float* __restrict__ cKV_t, float* __restrict__ kR_t) {
    const int KC = 128;
    __shared__ float sA[16 * KC];
    int nb = blockIdx.x;
    const float* W; float* C; int ld; int col0;
    if (nb < 3)      { W = W_DQ;  C = cQ;    ld = CQD;  col0 = nb * 512; }
    else if (nb < 4) { W = W_DKV; C = cKV_t; ld = CKVD; col0 = 0; }
    else             { W = W_KR;  C = kR_t;  ld = HDR;  col0 = (nb - 4) * 512; }
    int cn = col0 + threadIdx.x * 2;
    gemm16_core(hidden, HIDN, blockIdx.y * KC, KC, W, ld, cn, C, ld, cn, sA, threadIdx.x);
}

// Fused: qC = cQ@W_UQ_C, qR = cQ@W_UQ_R.  grid (12, 24), KC=64
__global__ __launch_bounds__(256) void proj_cq(
    const float* __restrict__ cQ,
    const float* __restrict__ W_UQ_C, const float* __restrict__ W_UQ_R,
    float* __restrict__ qC, float* __restrict__ qR) {
    const int KC = 64;
    __shared__ float sA[16 * KC];
    int nb = blockIdx.x;
    const float* W; float* C; int ld; int col0;
    if (nb < 8) { W = W_UQ_C; C = qC; ld = HDH; col0 = nb * 512; }
    else        { W = W_UQ_R; C = qR; ld = HDR; col0 = (nb - 8) * 512; }
    int cn = col0 + threadIdx.x * 2;
    gemm16_core(cQ, CQD, blockIdx.y * KC, KC, W, ld, cn, C, ld, cn, sA, threadIdx.x);
}

// Generic K/N-split gemm for the output projections. grid (N/512, K/KC)
template <int KC>
__global__ __launch_bounds__(256) void gemm16_gen(
    const float* __restrict__ A, const float* __restrict__ W,
    float* __restrict__ C, int K, int N) {
    __shared__ float sA[16 * KC];
    int cn = blockIdx.x * 512 + threadIdx.x * 2;
    gemm16_core(A, K, blockIdx.y * KC, KC, W, N, cn, C, N, cn, sA, threadIdx.x);
}

// qC_eff[b,k] = sum_c qC[b,c] * W_UK_C[k,c].  grid 256, wave -> (k, c-half)
__global__ __launch_bounds__(256) void qceff_v2(
    const float* __restrict__ qC, const float* __restrict__ WUK,
    float* __restrict__ qC_eff) {
    int wave = threadIdx.x >> 6, lane = threadIdx.x & 63;
    int k = blockIdx.x * 2 + (wave >> 1);
    int half = wave & 1;
    const float4* wrow = (const float4*)(WUK + (size_t)k * HDH + half * 2048);
    const float4* q4   = (const float4*)(qC + half * 2048);
    float acc[16];
#pragma unroll
    for (int b = 0; b < 16; ++b) acc[b] = 0.f;
#pragma unroll
    for (int it = 0; it < 8; ++it) {
        int c4 = it * 64 + lane;
        float4 w = wrow[c4];
#pragma unroll
        for (int b = 0; b < 16; ++b) {
            float4 q = q4[b * 1024 + c4];
            acc[b] += q.x * w.x + q.y * w.y + q.z * w.z + q.w * w.w;
        }
    }
#pragma unroll
    for (int b = 0; b < 16; ++b) {
        float v = acc[b];
#pragma unroll
        for (int off = 32; off > 0; off >>= 1) v += __shfl_down(v, off, 64);
        if (lane == 0) atomicAdd(&qC_eff[b * CKVD + k], v);
    }
}

// Fused score + cache copy.  grid (2049, 16), block 256
__global__ __launch_bounds__(256) void score_copy_kernel(
    const float* __restrict__ cached_cKV, const float* __restrict__ cached_kR,
    const float* __restrict__ cKV_t, const float* __restrict__ kR_t,
    const float* __restrict__ qC_eff, const float* __restrict__ qR,
    float* __restrict__ out_cKV, float* __restrict__ out_kR,
    float* __restrict__ scores) {
    int l = blockIdx.x;
    int b = blockIdx.y;
    int tid = threadIdx.x;
    int wave = tid >> 6, lane = tid & 63;
    const float4* ckv_row;
    const float4* kr_row;
    if (l < SEQL) {
        ckv_row = (const float4*)(cached_cKV + ((size_t)b * SEQL + l) * CKVD);
        kr_row  = (const float4*)(cached_kR  + ((size_t)b * SEQL + l) * HDR);
    } else {
        ckv_row = (const float4*)(cKV_t + b * CKVD);
        kr_row  = (const float4*)(kR_t + b * HDR);
    }
    float4* oc  = (float4*)(out_cKV + ((size_t)b * LP1 + l) * CKVD);
    float4* okr = (float4*)(out_kR  + ((size_t)b * LP1 + l) * HDR);
    const float4* qc4 = (const float4*)(qC_eff + b * CKVD);
    const float4* qr4 = (const float4*)(qR + b * HDR);
    float acc = 0.f;
    if (tid < 128) {
        float4 v = ckv_row[tid];
        float4 q = qc4[tid];
        acc += v.x * q.x + v.y * q.y + v.z * q.z + v.w * q.w;
        oc[tid] = v;
    }
#pragma unroll
    for (int j = 0; j < 2; ++j) {
        int i = tid + j * 256;
        float4 v = kr_row[i];
        float4 q = qr4[i];
        acc += v.x * q.x + v.y * q.y + v.z * q.z + v.w * q.w;
        okr[i] = v;
    }
#pragma unroll
    for (int off = 32; off > 0; off >>= 1) acc += __shfl_down(acc, off, 64);
    __shared__ float sRed[4];
    if (lane == 0) sRed[wave] = acc;
    __syncthreads();
    if (tid == 0)
        scores[b * LP1 + l] =
            (sRed[0] + sRed[1] + sRed[2] + sRed[3]) * 0.07216878364870323f;
}

__global__ __launch_bounds__(256) void softmax_kernel(
    const float* __restrict__ scores, float* __restrict__ probs) {
    int b = blockIdx.x;
    int tid = threadIdx.x;
    __shared__ float red[256];
    float m = -1e30f;
    for (int i = tid; i < LP1; i += 256) m = fmaxf(m, scores[b * LP1 + i]);
    red[tid] = m; __syncthreads();
    for (int s = 128; s > 0; s >>= 1) {
        if (tid < s) red[tid] = fmaxf(red[tid], red[tid + s]);
        __syncthreads();
    }
    m = red[0]; __syncthreads();
    float sum = 0.f;
    for (int i = tid; i < LP1; i += 256) sum += __expf(scores[b * LP1 + i] - m);
    red[tid] = sum; __syncthreads();
    for (int s = 128; s > 0; s >>= 1) {
        if (tid < s) red[tid] += red[tid + s];
        __syncthreads();
    }
    float inv = 1.0f / red[0];
    for (int i = tid; i < LP1; i += 256)
        probs[b * LP1 + i] = __expf(scores[b * LP1 + i] - m) * inv;
}

// ctx[b,:] = sum_l probs[b,l] * out_cKV[b,l,:].  grid (17, 16), block 256
__global__ __launch_bounds__(256) void ctx_kernel(
    const float* __restrict__ out_cKV, const float* __restrict__ probs,
    float* __restrict__ ctx) {
    int b = blockIdx.y;
    int tid = threadIdx.x;
    int c4 = tid & 127, sub = tid >> 7;
    int l0 = blockIdx.x * 128;
    int lend = l0 + 128; if (lend > LP1) lend = LP1;
    float4 acc = make_float4(0.f, 0.f, 0.f, 0.f);
    for (int l = l0 + sub; l < lend; l += 2) {
        float p = probs[b * LP1 + l];
        const float4* row = (const float4*)(out_cKV + ((size_t)b * LP1 + l) * CKVD);
        float4 v = row[c4];
        acc.x += p * v.x; acc.y += p * v.y; acc.z += p * v.z; acc.w += p * v.w;
    }
    float* dst = ctx + b * CKVD + c4 * 4;
    atomicAdd(dst + 0, acc.x);
    atomicAdd(dst + 1, acc.y);
    atomicAdd(dst + 2, acc.z);
    atomicAdd(dst + 3, acc.w);
}

extern "C" void kernel_launch(void* const* d_in, const int* in_sizes, int n_in,
                              void* d_out, int out_size, void* d_ws, size_t ws_size,
                              hipStream_t stream) {
    const float* hidden     = (const float*)d_in[0];
    const float* cached_cKV = (const float*)d_in[1];
    const float* cached_kR  = (const float*)d_in[2];
    const float* W_DQ   = (const float*)d_in[3];
    const float* W_DKV  = (const float*)d_in[4];
    const float* W_UQ_C = (const float*)d_in[5];
    const float* W_UQ_R = (const float*)d_in[6];
    const float* W_KR   = (const float*)d_in[7];
    const float* W_UK_C = (const float*)d_in[8];
    const float* W_UV_C = (const float*)d_in[9];
    const float* W_O    = (const float*)d_in[10];

    float* out     = (float*)d_out;                        // 16*4096
    float* out_cKV = out + BATCH * HDH;                    // 16*2049*512
    float* out_kR  = out_cKV + (size_t)BATCH * LP1 * CKVD; // 16*2049*2048

    float* ws      = (float*)d_ws;
    float* cQ      = ws;                       // 16*1536
    float* cKV_t   = cQ + BATCH * CQD;         // 16*512
    float* kR_t    = cKV_t + BATCH * CKVD;     // 16*2048
    float* qC      = kR_t + BATCH * HDR;       // 16*4096
    float* qR      = qC + BATCH * HDH;         // 16*2048
    float* qC_eff  = qR + BATCH * HDR;         // 16*512
    float* ctx     = qC_eff + BATCH * CKVD;    // 16*512
    float* tbuf    = ctx + BATCH * CKVD;       // 16*4096
    float* scores  = tbuf + BATCH * HDH;       // 16*2049
    float* probs   = scores + BATCH * LP1;     // 16*2049
    size_t n_ws_floats = (size_t)(probs + BATCH * LP1 - ws);

    hipMemsetAsync(d_ws, 0, n_ws_floats * sizeof(float), stream);
    hipMemsetAsync(d_out, 0, (size_t)BATCH * HDH * sizeof(float), stream);

    dim3 blk(256);
    proj_hidden<<<dim3(8, HIDN / 128), blk, 0, stream>>>(
        hidden, W_DQ, W_DKV, W_KR, cQ, cKV_t, kR_t);
    proj_cq<<<dim3(12, CQD / 64), blk, 0, stream>>>(cQ, W_UQ_C, W_UQ_R, qC, qR);
    qceff_v2<<<dim3(CKVD / 2), blk, 0, stream>>>(qC, W_UK_C, qC_eff);
    score_copy_kernel<<<dim3(LP1, BATCH), blk, 0, stream>>>(
        cached_cKV, cached_kR, cKV_t, kR_t, qC_eff, qR, out_cKV, out_kR, scores);
    softmax_kernel<<<dim3(BATCH), blk, 0, stream>>>(scores, probs);
    ctx_kernel<<<dim3((LP1 + 127) / 128, BATCH), blk, 0, stream>>>(out_cKV, probs, ctx);
    gemm16_gen<32><<<dim3(HDH / 512, CKVD / 32), blk, 0, stream>>>(
        ctx, W_UV_C, tbuf, CKVD, HDH);
    gemm16_gen<128><<<dim3(HIDN / 512, HDH / 128), blk, 0, stream>>>(
        tbuf, W_O, out, HDH, HIDN);
}